// Round 1
// baseline (118.652 us; speedup 1.0000x reference)
//
#include <hip/hip_runtime.h>
#include <math.h>

#define NB 4      // batch
#define NP 144    // output spatial positions (12x12)
#define KW 9      // kernel window size (3x3)
#define CIN 32
#define NC 32     // output capsules
#define NK 288    // KW*CIN children
#define ND 16     // pose dims
#define EPSI 1e-7f
#define NT 256

// One block per (b,p). Threads: c = t&31 (parent capsule), s = t>>5 (k-slice 0..7),
// each thread handles 36 k values (k = s*36 + j).
// EM routing with E-step fused into the following M-step (rr never materialized).
__global__ __launch_bounds__(NT) void convcaps_em_kernel(
    const float* __restrict__ g_act,    // [B,196,32]
    const float* __restrict__ g_pose,   // [B,196,32,16]
    const float* __restrict__ g_W,      // [288,32,16]
    const float* __restrict__ g_beta_a, // [32]
    const float* __restrict__ g_beta_v, // [32]
    const int*   __restrict__ g_cpm,    // [144,9]
    float* __restrict__ g_out)          // act [B*144*32] then pose [B*144*32*16]
{
    __shared__ float s_pose[NK][ND];    // 18432 B
    __shared__ float s_act[NK];         // 1152 B
    __shared__ float s_red[4][NC][34];  // 17408 B  (m1[0..15], m2[16..31], r0 at [32])
    __shared__ float s_mu[NC][17];      // 2176 B (padded stride 17: conflict-free)
    __shared__ float s_ivar[NC][17];
    __shared__ float s_lvar[NC][17];
    __shared__ float s_logout[NC];
    __shared__ float s_logdet[NC];
    __shared__ float s_outa[NC];
    __shared__ int   s_win[KW];

    const int bp   = blockIdx.x;
    const int b    = bp / NP;
    const int p    = bp - b * NP;
    const int t    = threadIdx.x;
    const int c    = t & 31;
    const int s    = t >> 5;
    const int wave = t >> 6;
    const int lane = t & 63;

    if (t < KW) s_win[t] = g_cpm[p * KW + t];
    __syncthreads();

    // ---- gather child poses + activations into LDS (coalesced per window) ----
    {
        const float* pb = g_pose + (size_t)b * (196 * CIN * ND);
        float* sp = &s_pose[0][0];
        for (int e = t; e < NK * ND; e += NT) {       // 4608 floats, 18/thread
            const int w = e >> 9;                     // CIN*ND = 512
            const int rem = e & 511;
            sp[e] = pb[s_win[w] * (CIN * ND) + rem];
        }
        const float* ab = g_act + (size_t)b * (196 * CIN);
        for (int e = t; e < NK; e += NT) {
            const int w = e >> 5;
            const int ci = e & 31;
            s_act[e] = ab[s_win[w] * CIN + ci];
        }
    }
    __syncthreads();

    const float log2pi16 = 16.0f * 1.8378770664093453f; // 16*log(2*pi)

    for (int it = 0; it < 3; ++it) {
        // ---------- M-step accumulation (E-step of prev iter fused in) ----------
        float r0 = 0.0f;
        float m1[ND], m2[ND];
        #pragma unroll
        for (int d = 0; d < ND; ++d) { m1[d] = 0.0f; m2[d] = 0.0f; }

        for (int j = 0; j < 36; ++j) {
            const int k = s * 36 + j;

            float pr[ND];
            {   // LDS vector loads (same addr across half-wave -> broadcast)
                const float4* pp = (const float4*)(&s_pose[k][0]);
                *(float4*)&pr[0]  = pp[0];
                *(float4*)&pr[4]  = pp[1];
                *(float4*)&pr[8]  = pp[2];
                *(float4*)&pr[12] = pp[3];
            }
            float wr[ND];
            {   // W[k][c][:] — 64B apart across lanes, L2-resident
                const float4* wp = (const float4*)(g_W + (size_t)(k * NC + c) * ND);
                *(float4*)&wr[0]  = wp[0];
                *(float4*)&wr[4]  = wp[1];
                *(float4*)&wr[8]  = wp[2];
                *(float4*)&wr[12] = wp[3];
            }

            // vote = pose(4x4) @ W(4x4): vote[i*4+l] = sum_j pr[i*4+j]*wr[j*4+l]
            float vote[ND];
            #pragma unroll
            for (int i = 0; i < 4; ++i) {
                #pragma unroll
                for (int l = 0; l < 4; ++l) {
                    float v =   pr[i*4+0] * wr[0*4+l];
                    v = fmaf(pr[i*4+1], wr[1*4+l], v);
                    v = fmaf(pr[i*4+2], wr[2*4+l], v);
                    v = fmaf(pr[i*4+3], wr[3*4+l], v);
                    vote[i*4+l] = v;
                }
            }

            float rr;
            if (it == 0) {
                rr = 1.0f / 32.0f;
            } else {
                // E-step using previous iteration's statistics
                float q = 0.0f;
                #pragma unroll
                for (int d = 0; d < ND; ++d) {
                    const float diff = vote[d] - s_mu[c][d];
                    q = fmaf(diff * diff, s_ivar[c][d], q);
                }
                float logit = s_logout[c] - 0.5f * (s_logdet[c] + q);
                // softmax over the 32 c's = the 32 lanes of this half-wave
                float mx = logit;
                mx = fmaxf(mx, __shfl_xor(mx, 16));
                mx = fmaxf(mx, __shfl_xor(mx, 8));
                mx = fmaxf(mx, __shfl_xor(mx, 4));
                mx = fmaxf(mx, __shfl_xor(mx, 2));
                mx = fmaxf(mx, __shfl_xor(mx, 1));
                const float e = __expf(logit - mx);
                float se = e;
                se += __shfl_xor(se, 16);
                se += __shfl_xor(se, 8);
                se += __shfl_xor(se, 4);
                se += __shfl_xor(se, 2);
                se += __shfl_xor(se, 1);
                rr = e / se;
            }

            const float rp = rr * s_act[k];
            r0 += rp;
            #pragma unroll
            for (int d = 0; d < ND; ++d) {
                const float rv = rp * vote[d];
                m1[d] += rv;
                m2[d] = fmaf(rv, vote[d], m2[d]);
            }
        }

        // ---------- reduce 8 slices: shfl over s-pairs, then 4 waves via LDS ----------
        r0 += __shfl_xor(r0, 32);
        #pragma unroll
        for (int d = 0; d < ND; ++d) {
            m1[d] += __shfl_xor(m1[d], 32);
            m2[d] += __shfl_xor(m2[d], 32);
        }
        __syncthreads();                  // prev s_red readers done
        if (lane < 32) {
            #pragma unroll
            for (int d = 0; d < ND; ++d) {
                s_red[wave][c][d]      = m1[d];
                s_red[wave][c][ND + d] = m2[d];
            }
            s_red[wave][c][32] = r0;
        }
        __syncthreads();

        // ---------- finalize mu/var per (c,d): 512 items, 2 per thread ----------
        for (int item = t; item < NC * ND; item += NT) {
            const int cc = item >> 4;
            const int d  = item & 15;
            const float am1 = s_red[0][cc][d] + s_red[1][cc][d] + s_red[2][cc][d] + s_red[3][cc][d];
            const float am2 = s_red[0][cc][ND+d] + s_red[1][cc][ND+d] + s_red[2][cc][ND+d] + s_red[3][cc][ND+d];
            const float ar0 = s_red[0][cc][32] + s_red[1][cc][32] + s_red[2][cc][32] + s_red[3][cc][32];
            const float rs  = ar0 + EPSI;
            const float mu  = am1 / rs;
            // exact expansion of sum rp*(v-mu)^2 = m2 - 2*mu*m1 + mu^2*r0
            const float var = (am2 - mu * (2.0f * am1 - mu * ar0)) / rs + EPSI;
            s_mu[cc][d]   = mu;
            s_ivar[cc][d] = 1.0f / var;
            s_lvar[cc][d] = __logf(var);
        }
        __syncthreads();

        // ---------- per-parent activation ----------
        if (t < NC) {
            const float ar0 = s_red[0][t][32] + s_red[1][t][32] + s_red[2][t][32] + s_red[3][t][32];
            const float rs  = ar0 + EPSI;
            float L = 0.0f;
            #pragma unroll
            for (int d = 0; d < ND; ++d) L += s_lvar[t][d];
            const float costsum  = rs * (16.0f * g_beta_v[t] + 0.5f * L);
            const float inv_temp = 1.0f + (float)it;       // 1, 2, 3
            const float x  = inv_temp * (g_beta_a[t] - costsum);
            const float oa = 1.0f / (1.0f + __expf(-x));
            s_outa[t]   = oa;
            s_logout[t] = __logf(oa + EPSI);
            s_logdet[t] = log2pi16 + L;
        }
        __syncthreads();
    }

    // ---------- write outputs: act [B,P,C] then pose [B,P,C,16] ----------
    const int base = (b * NP + p) * NC;
    if (t < NC) g_out[base + t] = s_outa[t];
    float* outpose = g_out + NB * NP * NC;
    for (int item = t; item < NC * ND; item += NT) {
        const int cc = item >> 4;
        const int d  = item & 15;
        outpose[(size_t)(base + cc) * ND + d] = s_mu[cc][d];
    }
}

extern "C" void kernel_launch(void* const* d_in, const int* in_sizes, int n_in,
                              void* d_out, int out_size, void* d_ws, size_t ws_size,
                              hipStream_t stream) {
    const float* in_act  = (const float*)d_in[0];
    const float* in_pose = (const float*)d_in[1];
    const float* W       = (const float*)d_in[2];
    const float* beta_a  = (const float*)d_in[3];
    const float* beta_v  = (const float*)d_in[4];
    const int*   cpm     = (const int*)d_in[5];
    float* out = (float*)d_out;

    convcaps_em_kernel<<<dim3(NB * NP), dim3(NT), 0, stream>>>(
        in_act, in_pose, W, beta_a, beta_v, cpm, out);
}